// Round 6
// baseline (254.866 us; speedup 1.0000x reference)
//
#include <hip/hip_runtime.h>
#include <math.h>

#define T_LEN 2048
#define WD 300
#define DTOT 2700
#define NPAT 50
#define H_DIM 100
#define NCLS 2
#define CCH 64      // chunks over time
#define SCH 32      // steps per chunk
#define TOTPAT 300
#define RSTRIDE 68  // pass2 LDS record stride
#define KP 320      // K padded for MFMA (10 x 32)
#define ASTR 40     // GEMM LDS row stride in ushorts (16B-aligned, bank-friendly)

typedef short bf16x8 __attribute__((ext_vector_type(8)));
typedef float f32x4 __attribute__((ext_vector_type(4)));

__device__ __forceinline__ float sigm(float x) { return 1.f / (1.f + __expf(-x)); }

__device__ __forceinline__ unsigned short f2bf(float x) {
    unsigned int u = __float_as_uint(x);
    u += 0x7fffu + ((u >> 16) & 1u);       // RN-even
    return (unsigned short)(u >> 16);
}
__device__ __forceinline__ float bf2f(unsigned short h) {
    return __uint_as_float(((unsigned int)h) << 16);
}

// ---------------------------------------------------------------------------
// Kernel 0: fused gather + split-bf16 prepack (+ zero the pass2 counter).
// ---------------------------------------------------------------------------
#define NA2 (T_LEN * (KP / 2))
#define NB2 (DTOT * (KP / 2))

__global__ __launch_bounds__(256) void prepack(const int* __restrict__ doc,
                                               const float* __restrict__ emb,
                                               const float* __restrict__ diags,
                                               unsigned short* __restrict__ Ah,
                                               unsigned short* __restrict__ Al,
                                               unsigned short* __restrict__ Bh,
                                               unsigned short* __restrict__ Bl,
                                               int* __restrict__ counter) {
    if (blockIdx.x == 0 && threadIdx.x == 0) *counter = 0;
    int gid = blockIdx.x * 256 + threadIdx.x;   // ushort2 item
    float2 v = make_float2(0.f, 0.f);
    unsigned short* ph;
    unsigned short* pl;
    size_t off;
    if (gid < NA2) {
        int t = gid / (KP / 2);
        int kk = (gid - t * (KP / 2)) * 2;
        if (kk < WD) v = *(const float2*)(emb + (size_t)doc[t] * WD + kk);
        off = (size_t)t * KP + kk;
        ph = Ah; pl = Al;
    } else {
        int b = gid - NA2;
        if (b >= NB2) return;
        int n = b / (KP / 2);
        int kk = (b - n * (KP / 2)) * 2;
        if (kk < WD) v = *(const float2*)(diags + (size_t)n * WD + kk);
        off = (size_t)n * KP + kk;
        ph = Bh; pl = Bl;
    }
    unsigned short h0 = f2bf(v.x), h1 = f2bf(v.y);
    unsigned short l0 = f2bf(v.x - bf2f(h0)), l1 = f2bf(v.y - bf2f(h1));
    ushort2 hv; hv.x = h0; hv.y = h1;
    ushort2 lv; lv.x = l0; lv.y = l1;
    *(ushort2*)(ph + off) = hv;
    *(ushort2*)(pl + off) = lv;
}

// ---------------------------------------------------------------------------
// Kernel 1: tm = sigmoid(A·B^T + bias) via split-bf16 MFMA.
// acc = Ah·Bh + Ah·Bl + Al·Bh. Block tile 128x128, 4 waves, each 64x64:
// per K-iter 16 ds_read_b128 feed 48 MFMA -> MFMA-bound (was 12:24, LDS-bound).
// Register prefetch of the next K-tile hides global latency under the MFMAs.
// ---------------------------------------------------------------------------
__global__ __launch_bounds__(256) void gemm_mfma(const unsigned short* __restrict__ Ah,
                                                 const unsigned short* __restrict__ Al,
                                                 const unsigned short* __restrict__ Bh,
                                                 const unsigned short* __restrict__ Bl,
                                                 const float* __restrict__ bias,
                                                 float* __restrict__ Cm) {
    __shared__ unsigned short sA[2][128][ASTR];
    __shared__ unsigned short sB[2][128][ASTR];
    int tid = threadIdx.x;
    int lane = tid & 63, wid = tid >> 6;
    int m0 = blockIdx.y * 128, n0 = blockIdx.x * 128;
    int wm = (wid >> 1) * 64;   // wave tile origin (local)
    int wn = (wid & 1) * 64;

    int srow = tid >> 2, sq = tid & 3;            // staging (row, 8-elem quad)
    int nr0 = n0 + srow;       if (nr0 > DTOT - 1) nr0 = DTOT - 1;
    int nr1 = n0 + srow + 64;  if (nr1 > DTOT - 1) nr1 = DTOT - 1;
    const size_t a0off = (size_t)(m0 + srow) * KP + sq * 8;
    const size_t a1off = (size_t)(m0 + srow + 64) * KP + sq * 8;
    const size_t b0off = (size_t)nr0 * KP + sq * 8;
    const size_t b1off = (size_t)nr1 * KP + sq * 8;

    f32x4 acc[4][4];
#pragma unroll
    for (int mi = 0; mi < 4; ++mi)
#pragma unroll
        for (int ni = 0; ni < 4; ++ni) acc[mi][ni] = (f32x4)(0.f);

    // prefetch k=0
    uint4 pah0 = *(const uint4*)(Ah + a0off);
    uint4 pah1 = *(const uint4*)(Ah + a1off);
    uint4 pal0 = *(const uint4*)(Al + a0off);
    uint4 pal1 = *(const uint4*)(Al + a1off);
    uint4 pbh0 = *(const uint4*)(Bh + b0off);
    uint4 pbh1 = *(const uint4*)(Bh + b1off);
    uint4 pbl0 = *(const uint4*)(Bl + b0off);
    uint4 pbl1 = *(const uint4*)(Bl + b1off);

    for (int k0 = 0; k0 < KP; k0 += 32) {
        __syncthreads();   // previous iter's frag reads done before overwrite
        *(uint4*)&sA[0][srow][sq * 8] = pah0;
        *(uint4*)&sA[0][srow + 64][sq * 8] = pah1;
        *(uint4*)&sA[1][srow][sq * 8] = pal0;
        *(uint4*)&sA[1][srow + 64][sq * 8] = pal1;
        *(uint4*)&sB[0][srow][sq * 8] = pbh0;
        *(uint4*)&sB[0][srow + 64][sq * 8] = pbh1;
        *(uint4*)&sB[1][srow][sq * 8] = pbl0;
        *(uint4*)&sB[1][srow + 64][sq * 8] = pbl1;
        __syncthreads();

        if (k0 + 32 < KP) {   // prefetch next tile; completes under the MFMAs
            int kn = k0 + 32;
            pah0 = *(const uint4*)(Ah + a0off + kn);
            pah1 = *(const uint4*)(Ah + a1off + kn);
            pal0 = *(const uint4*)(Al + a0off + kn);
            pal1 = *(const uint4*)(Al + a1off + kn);
            pbh0 = *(const uint4*)(Bh + b0off + kn);
            pbh1 = *(const uint4*)(Bh + b1off + kn);
            pbl0 = *(const uint4*)(Bl + b0off + kn);
            pbl1 = *(const uint4*)(Bl + b1off + kn);
        }

        int kc = (lane >> 4) * 8;
        int mr = lane & 15;
        bf16x8 ah[4], al[4], bh[4], bl[4];
#pragma unroll
        for (int mi = 0; mi < 4; ++mi) {
            ah[mi] = *(bf16x8*)&sA[0][wm + mi * 16 + mr][kc];
            al[mi] = *(bf16x8*)&sA[1][wm + mi * 16 + mr][kc];
        }
#pragma unroll
        for (int ni = 0; ni < 4; ++ni) {
            bh[ni] = *(bf16x8*)&sB[0][wn + ni * 16 + mr][kc];
            bl[ni] = *(bf16x8*)&sB[1][wn + ni * 16 + mr][kc];
        }
#pragma unroll
        for (int mi = 0; mi < 4; ++mi)
#pragma unroll
            for (int ni = 0; ni < 4; ++ni) {
                acc[mi][ni] = __builtin_amdgcn_mfma_f32_16x16x32_bf16(ah[mi], bh[ni], acc[mi][ni], 0, 0, 0);
                acc[mi][ni] = __builtin_amdgcn_mfma_f32_16x16x32_bf16(ah[mi], bl[ni], acc[mi][ni], 0, 0, 0);
                acc[mi][ni] = __builtin_amdgcn_mfma_f32_16x16x32_bf16(al[mi], bh[ni], acc[mi][ni], 0, 0, 0);
            }
    }

    // epilogue: C/D layout col=lane&15, row=(lane>>4)*4+r
    int mr = lane & 15;
    int rq = lane >> 4;
#pragma unroll
    for (int ni = 0; ni < 4; ++ni) {
        int col = n0 + wn + ni * 16 + mr;
        if (col < DTOT) {
            float bs = bias[col];
#pragma unroll
            for (int mi = 0; mi < 4; ++mi)
#pragma unroll
                for (int r = 0; r < 4; ++r) {
                    int row = m0 + wm + mi * 16 + rq * 4 + r;
                    Cm[(size_t)row * DTOT + col] = sigm(acc[mi][ni][r] + bs);
                }
        }
    }
}

// ---------------------------------------------------------------------------
// Kernel 2: chunked affine scan, pass 1 (LDS-staged).
// ---------------------------------------------------------------------------
template <int P, int PBP>
__device__ void pass1_blk(int chunk, int patblk, const float* __restrict__ tm,
                          const float* __restrict__ epsr, float sls, float esc,
                          float* __restrict__ ws2, int g, float* __restrict__ sT,
                          int tid) {
    constexpr int NP1 = P + 1;
    constexpr int dstart = 100 * ((P * (P - 1)) / 2 - 1);
    constexpr int ROWF = PBP * 2 * P;     // floats per t-row in LDS
    constexpr int RB4 = ROWF / 4;         // float4 per row
    constexpr int NF4 = SCH * RB4;

    const float* gbase = tm + (size_t)(chunk * SCH) * DTOT + dstart + patblk * ROWF;
#pragma unroll
    for (int i = 0; i < (NF4 + 63) / 64; ++i) {
        int f = i * 64 + tid;
        if (f < NF4) {
            int t = f / RB4;
            int q = f - t * RB4;
            *(float4*)&sT[t * ROWF + q * 4] = *(const float4*)(gbase + (size_t)t * DTOT + q * 4);
        }
    }
    __syncthreads();

    int patl = tid / NP1;
    int col = tid - patl * NP1;
    int pat = patblk * PBP + patl;
    if (patl < PBP && pat < NPAT) {
        float eps[P - 1];
#pragma unroll
        for (int j = 0; j < P - 1; ++j) eps[j] = esc * sigm(epsr[pat * (P - 1) + j]);

        float x[P];
#pragma unroll
        for (int i = 0; i < P; ++i) x[i] = 0.f;
        float inj = 0.f;
        if (col < P) x[col] = 1.f; else inj = 1.f;
        float qacc = 0.f;

        const float* lb = sT + patl * 2 * P;
#pragma unroll 4
        for (int t = 0; t < SCH; ++t) {
            float tv[2 * P];
            const float* row = lb + t * ROWF;
#pragma unroll
            for (int j = 0; j < P; ++j) {
                float2 u = *(const float2*)(row + 2 * j);
                tv[2 * j] = u.x;
                tv[2 * j + 1] = u.y;
            }
            float heps[P];
            heps[0] = x[0];
#pragma unroll
            for (int i = 1; i < P; ++i) heps[i] = fmaf(x[i - 1], eps[i - 1], x[i]);
            float res[P];
            res[0] = fmaf(heps[0], sls * tv[0], inj);
#pragma unroll
            for (int i = 1; i < P; ++i)
                res[i] = fmaf(heps[i - 1], tv[P + i - 1], heps[i] * (sls * tv[i]));
#pragma unroll
            for (int i = 0; i < P; ++i) x[i] = res[i];
            qacc += x[P - 1];
        }

        int gidx = g * NPAT + pat;
        float* dst = ws2 + ((size_t)(gidx * CCH + chunk)) * 64 + col * 8;
#pragma unroll
        for (int i = 0; i < P; ++i) dst[i] = x[i];
        dst[7] = qacc;
    }
}

// per-chunk block table: g=0..5 -> NB = {3,4,5,5,6,7}, prefix {0,3,7,12,17,23,30}
__global__ __launch_bounds__(64) void pass1_kernel(const float* __restrict__ tm,
                                                   const float* __restrict__ e2,
                                                   const float* __restrict__ e3,
                                                   const float* __restrict__ e4,
                                                   const float* __restrict__ e5,
                                                   const float* __restrict__ e6,
                                                   const float* __restrict__ e7,
                                                   const float* __restrict__ eps_scale,
                                                   const float* __restrict__ sl_scale,
                                                   float* __restrict__ ws2) {
    __shared__ float sT[3584];   // 14336 B, max (P=7: 32*8*14)
    int b = blockIdx.x;
    int chunk = b / 30;
    int r = b - chunk * 30;
    int tid = threadIdx.x;
    float sls = sigm(sl_scale[0]);
    float esc = sigm(eps_scale[0]);
    if (r < 3)       pass1_blk<2, 21>(chunk, r,      tm, e2, sls, esc, ws2, 0, sT, tid);
    else if (r < 7)  pass1_blk<3, 16>(chunk, r - 3,  tm, e3, sls, esc, ws2, 1, sT, tid);
    else if (r < 12) pass1_blk<4, 12>(chunk, r - 7,  tm, e4, sls, esc, ws2, 2, sT, tid);
    else if (r < 17) pass1_blk<5, 10>(chunk, r - 12, tm, e5, sls, esc, ws2, 3, sT, tid);
    else if (r < 23) pass1_blk<6, 9>(chunk, r - 17,  tm, e6, sls, esc, ws2, 4, sT, tid);
    else             pass1_blk<7, 8>(chunk, r - 23,  tm, e7, sls, esc, ws2, 5, sT, tid);
}

// ---------------------------------------------------------------------------
// Kernel 3: per-pattern tree fold (column-parallel) + fused MLP head.
// 300 blocks x 256 threads. Each block folds one pattern and publishes its
// score (threadfence + device-scope atomic). The last block to finish stages
// w1 into the re-used 120 KB LDS buffer and computes the logits.
// ---------------------------------------------------------------------------
template <int P>
__device__ void fold_pattern(const float* __restrict__ ws2, float* __restrict__ R,
                             float* __restrict__ scores, int gidx, int tid) {
    constexpr int NP1 = P + 1;
    const float4* src = (const float4*)(ws2 + (size_t)gidx * CCH * 64);
#pragma unroll
    for (int j = 0; j < 4; ++j) {
        int f = j * 256 + tid;
        int rec = f >> 4;
        int q4 = f & 15;
        *(float4*)&R[rec * RSTRIDE + q4 * 4] = src[f];
    }
    int pair = tid / NP1;
    int col = tid - pair * NP1;
    for (int g = 1; g < CCH; g <<= 1) {
        __syncthreads();
        int npairs = CCH / (2 * g);
        if (pair < npairs) {
            float* Ar = &R[(pair * 2 * g) * RSTRIDE];
            const float* Br = &R[(pair * 2 * g + g) * RSTRIDE];
            if (col < P) {
                float MAj[P], mc[P];
#pragma unroll
                for (int i = 0; i < P; ++i) { MAj[i] = Ar[col * 8 + i]; mc[i] = 0.f; }
                float qc = Ar[col * 8 + 7];
#pragma unroll
                for (int k = 0; k < P; ++k) {
                    float a = MAj[k];
#pragma unroll
                    for (int i = 0; i < P; ++i) mc[i] = fmaf(Br[k * 8 + i], a, mc[i]);
                    qc = fmaf(Br[k * 8 + 7], a, qc);
                }
#pragma unroll
                for (int i = 0; i < P; ++i) Ar[col * 8 + i] = mc[i];
                Ar[col * 8 + 7] = qc;
            } else {
                float vA[P], vc[P];
#pragma unroll
                for (int i = 0; i < P; ++i) { vA[i] = Ar[P * 8 + i]; vc[i] = Br[P * 8 + i]; }
                float rc = Ar[P * 8 + 7] + Br[P * 8 + 7];
#pragma unroll
                for (int k = 0; k < P; ++k) {
                    float a = vA[k];
#pragma unroll
                    for (int i = 0; i < P; ++i) vc[i] = fmaf(Br[k * 8 + i], a, vc[i]);
                    rc = fmaf(Br[k * 8 + 7], a, rc);
                }
#pragma unroll
                for (int i = 0; i < P; ++i) Ar[P * 8 + i] = vc[i];
                Ar[P * 8 + 7] = rc;
            }
        }
    }
    __syncthreads();
    if (tid == 0) scores[gidx] = R[0 * 8 + 7] + R[P * 8 + 7];  // q[0]·h0 + r
}

__global__ __launch_bounds__(256) void pass2_kernel(const float* __restrict__ ws2,
                                                    float* __restrict__ scores,
                                                    const float* __restrict__ w1,
                                                    const float* __restrict__ b1,
                                                    const float* __restrict__ w2,
                                                    const float* __restrict__ b2,
                                                    float* __restrict__ out,
                                                    int* __restrict__ counter) {
    __shared__ float big[TOTPAT * H_DIM];   // 120,000 B; fold uses first 4352 floats
    __shared__ float s_lds[TOTPAT];
    __shared__ float h_lds[H_DIM];
    __shared__ int flag;
    int gidx = blockIdx.x;
    int g = gidx / NPAT;
    int tid = threadIdx.x;
    switch (g) {
        case 0: fold_pattern<2>(ws2, big, scores, gidx, tid); break;
        case 1: fold_pattern<3>(ws2, big, scores, gidx, tid); break;
        case 2: fold_pattern<4>(ws2, big, scores, gidx, tid); break;
        case 3: fold_pattern<5>(ws2, big, scores, gidx, tid); break;
        case 4: fold_pattern<6>(ws2, big, scores, gidx, tid); break;
        case 5: fold_pattern<7>(ws2, big, scores, gidx, tid); break;
    }
    // publish score; last block runs the MLP head
    __threadfence();
    if (tid == 0) flag = atomicAdd(counter, 1);
    __syncthreads();
    if (flag == TOTPAT - 1) {
        __threadfence();   // acquire: all other blocks' score stores visible
        for (int f = tid; f < (TOTPAT * H_DIM) / 4; f += 256)
            *(float4*)&big[f * 4] = *(const float4*)(w1 + f * 4);
        for (int i = tid; i < TOTPAT; i += 256) s_lds[i] = scores[i];
        __syncthreads();
        if (tid < H_DIM) {
            float a = b1[tid];
#pragma unroll 6
            for (int i = 0; i < TOTPAT; ++i) a = fmaf(s_lds[i], big[i * H_DIM + tid], a);
            h_lds[tid] = fmaxf(a, 0.f);
        }
        __syncthreads();
        if (tid < NCLS) {
            float a = b2[tid];
            for (int j = 0; j < H_DIM; ++j) a = fmaf(h_lds[j], w2[j * NCLS + tid], a);
            out[tid] = a;
        }
    }
}

// ---------------------------------------------------------------------------
extern "C" void kernel_launch(void* const* d_in, const int* in_sizes, int n_in,
                              void* d_out, int out_size, void* d_ws, size_t ws_size,
                              hipStream_t stream) {
    const int* doc = (const int*)d_in[0];
    const float* emb = (const float*)d_in[1];
    const float* diags = (const float*)d_in[2];
    const float* bias = (const float*)d_in[3];
    const float* e2 = (const float*)d_in[4];
    const float* e3 = (const float*)d_in[5];
    const float* e4 = (const float*)d_in[6];
    const float* e5 = (const float*)d_in[7];
    const float* e6 = (const float*)d_in[8];
    const float* e7 = (const float*)d_in[9];
    const float* eps_scale = (const float*)d_in[10];
    const float* sl_scale = (const float*)d_in[11];
    const float* w1 = (const float*)d_in[12];
    const float* b1 = (const float*)d_in[13];
    const float* w2 = (const float*)d_in[14];
    const float* b2 = (const float*)d_in[15];
    float* out = (float*)d_out;

    // ws layout (bytes). Packs overlap ws2: packs are dead before pass1 writes ws2.
    char* ws = (char*)d_ws;
    float* tm = (float*)ws;                                     // [0, 22118400)
    float* ws2 = (float*)(ws + 22118400);                       // [22118400, 27033600)
    unsigned short* Ah = (unsigned short*)(ws + 22118400);      // 1310720
    unsigned short* Al = (unsigned short*)(ws + 23429120);      // 1310720
    unsigned short* Bh = (unsigned short*)(ws + 24739840);      // 1728000
    unsigned short* Bl = (unsigned short*)(ws + 26467840);      // 1728000 -> ends 28195840
    float* scores = (float*)(ws + 28195840);                    // 1200
    int* counter = (int*)(ws + 28197040);                       // 4

    hipLaunchKernelGGL(prepack, dim3((NA2 + NB2 + 255) / 256), dim3(256), 0, stream,
                       doc, emb, diags, Ah, Al, Bh, Bl, counter);
    hipLaunchKernelGGL(gemm_mfma, dim3((DTOT + 127) / 128, T_LEN / 128), dim3(256), 0,
                       stream, Ah, Al, Bh, Bl, bias, tm);
    hipLaunchKernelGGL(pass1_kernel, dim3(CCH * 30), dim3(64), 0, stream,
                       tm, e2, e3, e4, e5, e6, e7, eps_scale, sl_scale, ws2);
    hipLaunchKernelGGL(pass2_kernel, dim3(TOTPAT), dim3(256), 0, stream,
                       ws2, scores, w1, b1, w2, b2, out, counter);
}

// Round 7
// 236.690 us; speedup vs baseline: 1.0768x; 1.0768x over previous
//
#include <hip/hip_runtime.h>
#include <math.h>

#define T_LEN 2048
#define WD 300
#define DTOT 2700
#define NPAT 50
#define H_DIM 100
#define NCLS 2
#define CCH 64      // chunks over time
#define SCH 32      // steps per chunk
#define TOTPAT 300
#define RSTRIDE 68  // pass2a LDS record stride
#define KP 320      // K padded for MFMA (10 x 32)
#define ASTR 40     // GEMM LDS row stride in ushorts (16B-aligned, bank-friendly)

typedef short bf16x8 __attribute__((ext_vector_type(8)));
typedef float f32x4 __attribute__((ext_vector_type(4)));

__device__ __forceinline__ float sigm(float x) { return 1.f / (1.f + __expf(-x)); }

__device__ __forceinline__ unsigned short f2bf(float x) {
    unsigned int u = __float_as_uint(x);
    u += 0x7fffu + ((u >> 16) & 1u);       // RN-even
    return (unsigned short)(u >> 16);
}
__device__ __forceinline__ float bf2f(unsigned short h) {
    return __uint_as_float(((unsigned int)h) << 16);
}

// ---------------------------------------------------------------------------
// Kernel 0: fused gather + split-bf16 prepack.
// ---------------------------------------------------------------------------
#define NA2 (T_LEN * (KP / 2))
#define NB2 (DTOT * (KP / 2))

__global__ __launch_bounds__(256) void prepack(const int* __restrict__ doc,
                                               const float* __restrict__ emb,
                                               const float* __restrict__ diags,
                                               unsigned short* __restrict__ Ah,
                                               unsigned short* __restrict__ Al,
                                               unsigned short* __restrict__ Bh,
                                               unsigned short* __restrict__ Bl) {
    int gid = blockIdx.x * 256 + threadIdx.x;   // ushort2 item
    float2 v = make_float2(0.f, 0.f);
    unsigned short* ph;
    unsigned short* pl;
    size_t off;
    if (gid < NA2) {
        int t = gid / (KP / 2);
        int kk = (gid - t * (KP / 2)) * 2;
        if (kk < WD) v = *(const float2*)(emb + (size_t)doc[t] * WD + kk);
        off = (size_t)t * KP + kk;
        ph = Ah; pl = Al;
    } else {
        int b = gid - NA2;
        if (b >= NB2) return;
        int n = b / (KP / 2);
        int kk = (b - n * (KP / 2)) * 2;
        if (kk < WD) v = *(const float2*)(diags + (size_t)n * WD + kk);
        off = (size_t)n * KP + kk;
        ph = Bh; pl = Bl;
    }
    unsigned short h0 = f2bf(v.x), h1 = f2bf(v.y);
    unsigned short l0 = f2bf(v.x - bf2f(h0)), l1 = f2bf(v.y - bf2f(h1));
    ushort2 hv; hv.x = h0; hv.y = h1;
    ushort2 lv; lv.x = l0; lv.y = l1;
    *(ushort2*)(ph + off) = hv;
    *(ushort2*)(pl + off) = lv;
}

// ---------------------------------------------------------------------------
// Kernel 1: tm = sigmoid(A·B^T + bias) via split-bf16 MFMA.
// acc = Ah·Bh + Ah·Bl + Al·Bh. Tile 128x64, 4 waves, register prefetch.
// (128x128 tile measured SLOWER: 352-block grid quantizes badly on 256 CUs.)
// ---------------------------------------------------------------------------
__global__ __launch_bounds__(256) void gemm_mfma(const unsigned short* __restrict__ Ah,
                                                 const unsigned short* __restrict__ Al,
                                                 const unsigned short* __restrict__ Bh,
                                                 const unsigned short* __restrict__ Bl,
                                                 const float* __restrict__ bias,
                                                 float* __restrict__ Cm) {
    __shared__ unsigned short sA[2][128][ASTR];
    __shared__ unsigned short sB[2][64][ASTR];
    int tid = threadIdx.x;
    int lane = tid & 63, wid = tid >> 6;
    int m0 = blockIdx.y * 128, n0 = blockIdx.x * 64;
    int wm = (wid >> 1) * 64;   // wave tile origin (local)
    int wn = (wid & 1) * 32;

    int srow = tid >> 2, sq = tid & 3;            // staging row/quad
    int nr = n0 + srow; if (nr > DTOT - 1) nr = DTOT - 1;
    const size_t a0off = (size_t)(m0 + srow) * KP + sq * 8;
    const size_t a1off = (size_t)(m0 + srow + 64) * KP + sq * 8;
    const size_t boff = (size_t)nr * KP + sq * 8;

    f32x4 acc[4][2];
#pragma unroll
    for (int mi = 0; mi < 4; ++mi)
#pragma unroll
        for (int ni = 0; ni < 2; ++ni) acc[mi][ni] = (f32x4)(0.f);

    // prefetch k=0
    uint4 pah0 = *(const uint4*)(Ah + a0off);
    uint4 pah1 = *(const uint4*)(Ah + a1off);
    uint4 pal0 = *(const uint4*)(Al + a0off);
    uint4 pal1 = *(const uint4*)(Al + a1off);
    uint4 pbh = *(const uint4*)(Bh + boff);
    uint4 pbl = *(const uint4*)(Bl + boff);

    for (int k0 = 0; k0 < KP; k0 += 32) {
        __syncthreads();   // previous iter's frag reads done before overwrite
        *(uint4*)&sA[0][srow][sq * 8] = pah0;
        *(uint4*)&sA[0][srow + 64][sq * 8] = pah1;
        *(uint4*)&sA[1][srow][sq * 8] = pal0;
        *(uint4*)&sA[1][srow + 64][sq * 8] = pal1;
        *(uint4*)&sB[0][srow][sq * 8] = pbh;
        *(uint4*)&sB[1][srow][sq * 8] = pbl;
        __syncthreads();

        if (k0 + 32 < KP) {   // prefetch next tile; completes under the MFMAs
            int kn = k0 + 32;
            pah0 = *(const uint4*)(Ah + a0off + kn);
            pah1 = *(const uint4*)(Ah + a1off + kn);
            pal0 = *(const uint4*)(Al + a0off + kn);
            pal1 = *(const uint4*)(Al + a1off + kn);
            pbh = *(const uint4*)(Bh + boff + kn);
            pbl = *(const uint4*)(Bl + boff + kn);
        }

        int kc = (lane >> 4) * 8;
        int mr = lane & 15;
        bf16x8 ah[4], al[4], bh[2], bl[2];
#pragma unroll
        for (int mi = 0; mi < 4; ++mi) {
            ah[mi] = *(bf16x8*)&sA[0][wm + mi * 16 + mr][kc];
            al[mi] = *(bf16x8*)&sA[1][wm + mi * 16 + mr][kc];
        }
#pragma unroll
        for (int ni = 0; ni < 2; ++ni) {
            bh[ni] = *(bf16x8*)&sB[0][wn + ni * 16 + mr][kc];
            bl[ni] = *(bf16x8*)&sB[1][wn + ni * 16 + mr][kc];
        }
#pragma unroll
        for (int mi = 0; mi < 4; ++mi)
#pragma unroll
            for (int ni = 0; ni < 2; ++ni) {
                acc[mi][ni] = __builtin_amdgcn_mfma_f32_16x16x32_bf16(ah[mi], bh[ni], acc[mi][ni], 0, 0, 0);
                acc[mi][ni] = __builtin_amdgcn_mfma_f32_16x16x32_bf16(ah[mi], bl[ni], acc[mi][ni], 0, 0, 0);
                acc[mi][ni] = __builtin_amdgcn_mfma_f32_16x16x32_bf16(al[mi], bh[ni], acc[mi][ni], 0, 0, 0);
            }
    }

    // epilogue: C/D layout col=lane&15, row=(lane>>4)*4+r
    int mr = lane & 15;
    int rq = lane >> 4;
#pragma unroll
    for (int ni = 0; ni < 2; ++ni) {
        int col = n0 + wn + ni * 16 + mr;
        int cc = col < DTOT ? col : DTOT - 1;
        float bs = bias[cc];
        if (col < DTOT) {
#pragma unroll
            for (int mi = 0; mi < 4; ++mi)
#pragma unroll
                for (int r = 0; r < 4; ++r) {
                    int row = m0 + wm + mi * 16 + rq * 4 + r;
                    Cm[(size_t)row * DTOT + col] = sigm(acc[mi][ni][r] + bs);
                }
        }
    }
}

// ---------------------------------------------------------------------------
// Kernel 2: chunked affine scan, pass 1 (LDS-staged).
// ---------------------------------------------------------------------------
template <int P, int PBP>
__device__ void pass1_blk(int chunk, int patblk, const float* __restrict__ tm,
                          const float* __restrict__ epsr, float sls, float esc,
                          float* __restrict__ ws2, int g, float* __restrict__ sT,
                          int tid) {
    constexpr int NP1 = P + 1;
    constexpr int dstart = 100 * ((P * (P - 1)) / 2 - 1);
    constexpr int ROWF = PBP * 2 * P;     // floats per t-row in LDS
    constexpr int RB4 = ROWF / 4;         // float4 per row
    constexpr int NF4 = SCH * RB4;

    const float* gbase = tm + (size_t)(chunk * SCH) * DTOT + dstart + patblk * ROWF;
#pragma unroll
    for (int i = 0; i < (NF4 + 63) / 64; ++i) {
        int f = i * 64 + tid;
        if (f < NF4) {
            int t = f / RB4;
            int q = f - t * RB4;
            *(float4*)&sT[t * ROWF + q * 4] = *(const float4*)(gbase + (size_t)t * DTOT + q * 4);
        }
    }
    __syncthreads();

    int patl = tid / NP1;
    int col = tid - patl * NP1;
    int pat = patblk * PBP + patl;
    if (patl < PBP && pat < NPAT) {
        float eps[P - 1];
#pragma unroll
        for (int j = 0; j < P - 1; ++j) eps[j] = esc * sigm(epsr[pat * (P - 1) + j]);

        float x[P];
#pragma unroll
        for (int i = 0; i < P; ++i) x[i] = 0.f;
        float inj = 0.f;
        if (col < P) x[col] = 1.f; else inj = 1.f;
        float qacc = 0.f;

        const float* lb = sT + patl * 2 * P;
#pragma unroll 4
        for (int t = 0; t < SCH; ++t) {
            float tv[2 * P];
            const float* row = lb + t * ROWF;
#pragma unroll
            for (int j = 0; j < P; ++j) {
                float2 u = *(const float2*)(row + 2 * j);
                tv[2 * j] = u.x;
                tv[2 * j + 1] = u.y;
            }
            float heps[P];
            heps[0] = x[0];
#pragma unroll
            for (int i = 1; i < P; ++i) heps[i] = fmaf(x[i - 1], eps[i - 1], x[i]);
            float res[P];
            res[0] = fmaf(heps[0], sls * tv[0], inj);
#pragma unroll
            for (int i = 1; i < P; ++i)
                res[i] = fmaf(heps[i - 1], tv[P + i - 1], heps[i] * (sls * tv[i]));
#pragma unroll
            for (int i = 0; i < P; ++i) x[i] = res[i];
            qacc += x[P - 1];
        }

        int gidx = g * NPAT + pat;
        float* dst = ws2 + ((size_t)(gidx * CCH + chunk)) * 64 + col * 8;
#pragma unroll
        for (int i = 0; i < P; ++i) dst[i] = x[i];
        dst[7] = qacc;
    }
}

// per-chunk block table: g=0..5 -> NB = {3,4,5,5,6,7}, prefix {0,3,7,12,17,23,30}
__global__ __launch_bounds__(64) void pass1_kernel(const float* __restrict__ tm,
                                                   const float* __restrict__ e2,
                                                   const float* __restrict__ e3,
                                                   const float* __restrict__ e4,
                                                   const float* __restrict__ e5,
                                                   const float* __restrict__ e6,
                                                   const float* __restrict__ e7,
                                                   const float* __restrict__ eps_scale,
                                                   const float* __restrict__ sl_scale,
                                                   float* __restrict__ ws2) {
    __shared__ float sT[3584];   // 14336 B, max (P=7: 32*8*14)
    int b = blockIdx.x;
    int chunk = b / 30;
    int r = b - chunk * 30;
    int tid = threadIdx.x;
    float sls = sigm(sl_scale[0]);
    float esc = sigm(eps_scale[0]);
    if (r < 3)       pass1_blk<2, 21>(chunk, r,      tm, e2, sls, esc, ws2, 0, sT, tid);
    else if (r < 7)  pass1_blk<3, 16>(chunk, r - 3,  tm, e3, sls, esc, ws2, 1, sT, tid);
    else if (r < 12) pass1_blk<4, 12>(chunk, r - 7,  tm, e4, sls, esc, ws2, 2, sT, tid);
    else if (r < 17) pass1_blk<5, 10>(chunk, r - 12, tm, e5, sls, esc, ws2, 3, sT, tid);
    else if (r < 23) pass1_blk<6, 9>(chunk, r - 17,  tm, e6, sls, esc, ws2, 4, sT, tid);
    else             pass1_blk<7, 8>(chunk, r - 23,  tm, e7, sls, esc, ws2, 5, sT, tid);
}

// ---------------------------------------------------------------------------
// Kernel 3a: per-pattern tree fold, column-parallel compose.
// ---------------------------------------------------------------------------
template <int P>
__device__ void fold_pattern(const float* __restrict__ ws2, float* __restrict__ R,
                             float* __restrict__ scores, int gidx, int tid) {
    constexpr int NP1 = P + 1;
    const float4* src = (const float4*)(ws2 + (size_t)gidx * CCH * 64);
#pragma unroll
    for (int j = 0; j < 4; ++j) {
        int f = j * 256 + tid;
        int rec = f >> 4;
        int q4 = f & 15;
        *(float4*)&R[rec * RSTRIDE + q4 * 4] = src[f];
    }
    int pair = tid / NP1;
    int col = tid - pair * NP1;
    for (int g = 1; g < CCH; g <<= 1) {
        __syncthreads();
        int npairs = CCH / (2 * g);
        if (pair < npairs) {
            float* Ar = &R[(pair * 2 * g) * RSTRIDE];
            const float* Br = &R[(pair * 2 * g + g) * RSTRIDE];
            if (col < P) {
                float MAj[P], mc[P];
#pragma unroll
                for (int i = 0; i < P; ++i) { MAj[i] = Ar[col * 8 + i]; mc[i] = 0.f; }
                float qc = Ar[col * 8 + 7];
#pragma unroll
                for (int k = 0; k < P; ++k) {
                    float a = MAj[k];
#pragma unroll
                    for (int i = 0; i < P; ++i) mc[i] = fmaf(Br[k * 8 + i], a, mc[i]);
                    qc = fmaf(Br[k * 8 + 7], a, qc);
                }
#pragma unroll
                for (int i = 0; i < P; ++i) Ar[col * 8 + i] = mc[i];
                Ar[col * 8 + 7] = qc;
            } else {
                float vA[P], vc[P];
#pragma unroll
                for (int i = 0; i < P; ++i) { vA[i] = Ar[P * 8 + i]; vc[i] = Br[P * 8 + i]; }
                float rc = Ar[P * 8 + 7] + Br[P * 8 + 7];
#pragma unroll
                for (int k = 0; k < P; ++k) {
                    float a = vA[k];
#pragma unroll
                    for (int i = 0; i < P; ++i) vc[i] = fmaf(Br[k * 8 + i], a, vc[i]);
                    rc = fmaf(Br[k * 8 + 7], a, rc);
                }
#pragma unroll
                for (int i = 0; i < P; ++i) Ar[P * 8 + i] = vc[i];
                Ar[P * 8 + 7] = rc;
            }
        }
    }
    __syncthreads();
    if (tid == 0) scores[gidx] = R[0 * 8 + 7] + R[P * 8 + 7];  // q[0]·h0 + r
}

__global__ __launch_bounds__(256) void pass2a_kernel(const float* __restrict__ ws2,
                                                     float* __restrict__ scores) {
    __shared__ float R[CCH * RSTRIDE];
    int gidx = blockIdx.x;
    int g = gidx / NPAT;
    int tid = threadIdx.x;
    switch (g) {
        case 0: fold_pattern<2>(ws2, R, scores, gidx, tid); break;
        case 1: fold_pattern<3>(ws2, R, scores, gidx, tid); break;
        case 2: fold_pattern<4>(ws2, R, scores, gidx, tid); break;
        case 3: fold_pattern<5>(ws2, R, scores, gidx, tid); break;
        case 4: fold_pattern<6>(ws2, R, scores, gidx, tid); break;
        case 5: fold_pattern<7>(ws2, R, scores, gidx, tid); break;
    }
}

// ---------------------------------------------------------------------------
// Kernel 3b: MLP head, LDS-staged w1.
// ---------------------------------------------------------------------------
__global__ __launch_bounds__(256) void mlp_kernel(const float* __restrict__ scores,
                                                  const float* __restrict__ w1,
                                                  const float* __restrict__ b1,
                                                  const float* __restrict__ w2,
                                                  const float* __restrict__ b2,
                                                  float* __restrict__ out) {
    __shared__ float w1_lds[TOTPAT * H_DIM];   // 120,000 B
    __shared__ float s_lds[TOTPAT];
    __shared__ float h_lds[H_DIM];
    int tid = threadIdx.x;
    // stage w1: 7500 float4, independent
    for (int f = tid; f < (TOTPAT * H_DIM) / 4; f += 256)
        *(float4*)&w1_lds[f * 4] = *(const float4*)(w1 + f * 4);
    for (int i = tid; i < TOTPAT; i += 256) s_lds[i] = scores[i];
    __syncthreads();
    if (tid < H_DIM) {
        float a = b1[tid];
#pragma unroll 6
        for (int i = 0; i < TOTPAT; ++i) a = fmaf(s_lds[i], w1_lds[i * H_DIM + tid], a);
        h_lds[tid] = fmaxf(a, 0.f);
    }
    __syncthreads();
    if (tid < NCLS) {
        float a = b2[tid];
        for (int j = 0; j < H_DIM; ++j) a = fmaf(h_lds[j], w2[j * NCLS + tid], a);
        out[tid] = a;
    }
}

// ---------------------------------------------------------------------------
extern "C" void kernel_launch(void* const* d_in, const int* in_sizes, int n_in,
                              void* d_out, int out_size, void* d_ws, size_t ws_size,
                              hipStream_t stream) {
    const int* doc = (const int*)d_in[0];
    const float* emb = (const float*)d_in[1];
    const float* diags = (const float*)d_in[2];
    const float* bias = (const float*)d_in[3];
    const float* e2 = (const float*)d_in[4];
    const float* e3 = (const float*)d_in[5];
    const float* e4 = (const float*)d_in[6];
    const float* e5 = (const float*)d_in[7];
    const float* e6 = (const float*)d_in[8];
    const float* e7 = (const float*)d_in[9];
    const float* eps_scale = (const float*)d_in[10];
    const float* sl_scale = (const float*)d_in[11];
    const float* w1 = (const float*)d_in[12];
    const float* b1 = (const float*)d_in[13];
    const float* w2 = (const float*)d_in[14];
    const float* b2 = (const float*)d_in[15];
    float* out = (float*)d_out;

    // ws layout (bytes). Packs overlap ws2: packs are dead before pass1 writes ws2.
    char* ws = (char*)d_ws;
    float* tm = (float*)ws;                                     // [0, 22118400)
    float* ws2 = (float*)(ws + 22118400);                       // [22118400, 27033600)
    unsigned short* Ah = (unsigned short*)(ws + 22118400);      // 1310720
    unsigned short* Al = (unsigned short*)(ws + 23429120);      // 1310720
    unsigned short* Bh = (unsigned short*)(ws + 24739840);      // 1728000
    unsigned short* Bl = (unsigned short*)(ws + 26467840);      // 1728000 -> ends 28195840
    float* scores = (float*)(ws + 28195840);                    // 1200

    hipLaunchKernelGGL(prepack, dim3((NA2 + NB2 + 255) / 256), dim3(256), 0, stream,
                       doc, emb, diags, Ah, Al, Bh, Bl);
    hipLaunchKernelGGL(gemm_mfma, dim3((DTOT + 63) / 64, T_LEN / 128), dim3(256), 0,
                       stream, Ah, Al, Bh, Bl, bias, tm);
    hipLaunchKernelGGL(pass1_kernel, dim3(CCH * 30), dim3(64), 0, stream,
                       tm, e2, e3, e4, e5, e6, e7, eps_scale, sl_scale, ws2);
    hipLaunchKernelGGL(pass2a_kernel, dim3(TOTPAT), dim3(256), 0, stream,
                       ws2, scores);
    hipLaunchKernelGGL(mlp_kernel, dim3(1), dim3(256), 0, stream,
                       scores, w1, b1, w2, b2, out);
}